// Round 15
// baseline (41.950 us; speedup 1.0000x reference)
//
#include <hip/hip_runtime.h>
#include <hip/hip_fp16.h>

#define IN_F   4096
#define OUT_F  11008
#define BATCH  16
#define GROUPS 32                    // 4096 / 128
#define PPR    2048                  // packed int32 per output row (IN_F/2)

typedef __attribute__((ext_vector_type(8))) _Float16 half8;
typedef __attribute__((ext_vector_type(2))) _Float16 h2;
typedef __attribute__((ext_vector_type(4))) float    float4_t;
typedef __attribute__((ext_vector_type(4))) int      int4_t;
typedef __attribute__((ext_vector_type(4))) unsigned uint4_t;

__device__ inline h2 cvt2(float a, float b) {
    return __builtin_bit_cast(h2, __builtin_amdgcn_cvt_pkrtz(a, b));
}

// async global->LDS, 16B/lane, dest = uniform base + lane*16.
// aux=2 = NT (non-temporal): q is a zero-reuse stream.
#define GLOAD_LDS_NT(srcp, ldsp) \
    __builtin_amdgcn_global_load_lds( \
        (const __attribute__((address_space(1))) void*)(srcp), \
        (__attribute__((address_space(3))) void*)(ldsp), 16, 0, 2)

// ---- SINGLE-KERNEL gemm (R10 structure + in-register x conversion).
// Block = otile, 4 waves, K = 8 chunks x 512 cols, LDS dbuf 2x16KB.
// Wave w: group c*4+w of each chunk (128 cols, 4 MFMA steps). q staged
// contiguously (1KB/row/instr, NT) with source-side XOR slot swizzle (T21);
// x loaded as f32 straight from L2-resident input (2 dwordx4/step) and
// converted via cvt_pkrtz — no pre-pass dispatch. Counted vmcnt(12) keeps
// the next chunk's 12 VMEM ops in flight across every barrier.
__global__ __launch_bounds__(256, 2) void gptq_gemm_full(
    const float* __restrict__ x, const int* __restrict__ qw,
    const float* __restrict__ scales, const float* __restrict__ zeros,
    const float* __restrict__ bias, float* __restrict__ out)
{
    __shared__ int   lq[2][16 * 256];    // 2 x 16KB swizzled q tiles
    __shared__ float red[4][16][17];

    const int tid  = threadIdx.x;
    const int lane = tid & 63, wave = tid >> 6;
    const int otile = blockIdx.x;
    const int ln = lane & 15, lk = lane >> 4;
    const int o  = otile * 16 + ln;
    const int x3 = ln & 7;

    // group constants: chunk c -> group c*4 + wave
    h2 s2g[8], c2g[8];
    #pragma unroll
    for (int c = 0; c < 8; ++c) {
        const float s = scales[o * GROUPS + c * 4 + wave];
        const float z = zeros [o * GROUPS + c * 4 + wave];
        s2g[c] = cvt2(s, s);
        c2g[c] = cvt2(-z * s, -z * s);        // w = q*s + (-z*s)
    }
    const h2 k1024 = { (_Float16)1024.0f, (_Float16)1024.0f };

    asm volatile("s_waitcnt vmcnt(0)" ::: "memory");   // const loads retired
    __builtin_amdgcn_sched_barrier(0);                 // -> vmcnt exact

    float4_t xf[2][8];                   // f32 x fragments, 2-chunk dbuf
    float4_t acc = {0.f, 0.f, 0.f, 0.f};

// stage chunk C: wave stages rows 4w..4w+3, 1KB contiguous each, NT.
// LDS slot s of row r holds global slot s^(r&7)  (src inv-swizzle, T21).
#define STAGE(C, BUF) { \
    _Pragma("unroll") \
    for (int i = 0; i < 4; ++i) { \
        const int r = wave * 4 + i; \
        const int* src = qw + (otile * 16 + r) * PPR + (C) * 256 \
                       + ((lane ^ (r & 7)) * 4); \
        GLOAD_LDS_NT(src, &lq[BUF][r * 256]); \
    } \
    __builtin_amdgcn_sched_barrier(0); }

// 8 f32 x-loads for chunk C (2 per step): lane (ln,lk) step t reads
// x[ln][C*512 + wave*128 + t*32 + lk*8 .. +8)  (32B = 2 dwordx4)
#define XLOAD(C, BUF) { \
    const char* xc = (const char*)x \
        + ((ln * IN_F + (C) * 512 + wave * 128 + lk * 8) << 2); \
    asm volatile("global_load_dwordx4 %0, %1, off"            : "=v"(xf[BUF][0]) : "v"(xc)); \
    asm volatile("global_load_dwordx4 %0, %1, off offset:16"  : "=v"(xf[BUF][1]) : "v"(xc)); \
    asm volatile("global_load_dwordx4 %0, %1, off offset:128" : "=v"(xf[BUF][2]) : "v"(xc)); \
    asm volatile("global_load_dwordx4 %0, %1, off offset:144" : "=v"(xf[BUF][3]) : "v"(xc)); \
    asm volatile("global_load_dwordx4 %0, %1, off offset:256" : "=v"(xf[BUF][4]) : "v"(xc)); \
    asm volatile("global_load_dwordx4 %0, %1, off offset:272" : "=v"(xf[BUF][5]) : "v"(xc)); \
    asm volatile("global_load_dwordx4 %0, %1, off offset:384" : "=v"(xf[BUF][6]) : "v"(xc)); \
    asm volatile("global_load_dwordx4 %0, %1, off offset:400" : "=v"(xf[BUF][7]) : "v"(xc)); \
    __builtin_amdgcn_sched_barrier(0); }

#define WAITV12 { asm volatile("s_waitcnt vmcnt(12)" ::: "memory"); \
                  __builtin_amdgcn_sched_barrier(0); }
#define WAITV0  { asm volatile("s_waitcnt vmcnt(0)"  ::: "memory"); \
                  __builtin_amdgcn_sched_barrier(0); }
#define BARR    { __builtin_amdgcn_s_barrier(); \
                  __builtin_amdgcn_sched_barrier(0); }

// 4 steps of chunk C from buffer BUF: swizzled ds_read_b128 + f32->f16 A +
// magic-number dequant B + MFMA
#define COMPUTE(C, BUF) { \
    _Pragma("unroll") \
    for (int t = 0; t < 4; ++t) { \
        const int4_t v = *(const int4_t*)((const char*)lq + (BUF) * 16384 \
            + ln * 1024 + (((wave * 16 + t * 4 + lk) ^ x3) << 4)); \
        const float4_t a0 = xf[BUF][t * 2], a1 = xf[BUF][t * 2 + 1]; \
        half8 af; \
        { h2 p0 = cvt2(a0.x, a0.y), p1 = cvt2(a0.z, a0.w); \
          h2 p2 = cvt2(a1.x, a1.y), p3 = cvt2(a1.z, a1.w); \
          af[0]=p0[0]; af[1]=p0[1]; af[2]=p1[0]; af[3]=p1[1]; \
          af[4]=p2[0]; af[5]=p2[1]; af[6]=p3[0]; af[7]=p3[1]; } \
        uint4_t bw; \
        _Pragma("unroll") \
        for (int i = 0; i < 4; ++i) { \
            const unsigned pv = (unsigned)v[i]; \
            const unsigned u = (pv & 0xFu) | ((pv << 12) & 0xF0000u) \
                             | 0x64006400u;            /* {1024+qlo,1024+qhi} */ \
            h2 q = __builtin_bit_cast(h2, u) - k1024;  /* exact {qlo,qhi} */ \
            h2 w = q * s2g[C] + c2g[C];                /* v_pk_fma_f16 */ \
            bw[i] = __builtin_bit_cast(unsigned, w); \
        } \
        acc = __builtin_amdgcn_mfma_f32_16x16x32_f16( \
            af, __builtin_bit_cast(half8, bw), acc, 0, 0, 0); \
    } }

    STAGE(0, 0) XLOAD(0, 0)      // 12 in flight
    STAGE(1, 1) XLOAD(1, 1)      // 24 in flight

    WAITV12 BARR COMPUTE(0, 0) BARR STAGE(2, 0) XLOAD(2, 0)
    WAITV12 BARR COMPUTE(1, 1) BARR STAGE(3, 1) XLOAD(3, 1)
    WAITV12 BARR COMPUTE(2, 0) BARR STAGE(4, 0) XLOAD(4, 0)
    WAITV12 BARR COMPUTE(3, 1) BARR STAGE(5, 1) XLOAD(5, 1)
    WAITV12 BARR COMPUTE(4, 0) BARR STAGE(6, 0) XLOAD(6, 0)
    WAITV12 BARR COMPUTE(5, 1) BARR STAGE(7, 1) XLOAD(7, 1)
    WAITV12 BARR COMPUTE(6, 0) BARR
    WAITV0  BARR COMPUTE(7, 1)

#undef STAGE
#undef XLOAD
#undef WAITV12
#undef WAITV0
#undef BARR
#undef COMPUTE

    // cross-wave k-reduce; C/D layout (m89-verified): lane holds D[(l>>4)*4+r][l&15]
    #pragma unroll
    for (int r = 0; r < 4; ++r) red[wave][lk * 4 + r][ln] = acc[r];
    __syncthreads();

    const int row = tid >> 4, col = tid & 15;
    const float sum = red[0][row][col] + red[1][row][col]
                    + red[2][row][col] + red[3][row][col];
    const int oo = otile * 16 + col;
    out[row * OUT_F + oo] = sum + bias[oo];
}

extern "C" void kernel_launch(void* const* d_in, const int* in_sizes, int n_in,
                              void* d_out, int out_size, void* d_ws, size_t ws_size,
                              hipStream_t stream) {
    const float* x      = (const float*)d_in[0];
    const int*   qwgt   = (const int*)d_in[1];
    const float* scales = (const float*)d_in[2];
    const float* zeros  = (const float*)d_in[3];
    const float* bias   = (const float*)d_in[4];
    float* out = (float*)d_out;

    hipLaunchKernelGGL(gptq_gemm_full, dim3(OUT_F / 16), dim3(256), 0, stream,
                       x, qwgt, scales, zeros, bias, out);
}

// Round 16
// 29.751 us; speedup vs baseline: 1.4100x; 1.4100x over previous
//
#include <hip/hip_runtime.h>
#include <hip/hip_fp16.h>

#define IN_F   4096
#define OUT_F  11008
#define BATCH  16
#define GROUPS 32                    // 4096 / 128
#define PPR    2048                  // packed int32 per output row (IN_F/2)

typedef __attribute__((ext_vector_type(8))) _Float16 half8;
typedef __attribute__((ext_vector_type(2))) _Float16 h2;
typedef __attribute__((ext_vector_type(4))) float    float4_t;
typedef __attribute__((ext_vector_type(4))) int      int4_t;
typedef __attribute__((ext_vector_type(4))) unsigned uint4_t;

__device__ inline h2 cvt2(float a, float b) {
    return __builtin_bit_cast(h2, __builtin_amdgcn_cvt_pkrtz(a, b));
}

// async global->LDS, 16B per lane, dest = uniform base + lane*16
#define GLOAD_LDS(srcp, ldsp) \
    __builtin_amdgcn_global_load_lds( \
        (const __attribute__((address_space(1))) void*)(srcp), \
        (__attribute__((address_space(3))) void*)(ldsp), 16, 0, 0)

// ---- pre-pass: x (16x4096 f32) -> f16 table in FRAGMENT order ----
// step s (32 k-cols), lane l: xp[s*512 + l*8 .. +8) = f16 x[b=l&15]
// [k = s*32 + (l>>4)*8 .. +8). Gemm A-fragment load = ONE contiguous 1KB req.
// (R15 lesson: fusing this back into the gemm recreates scattered 32B reads
// across 16 rows -> 40% regression. Keep the separate pre-pass.)
__global__ __launch_bounds__(256) void xcvt_perm(const float* __restrict__ x,
                                                 _Float16* __restrict__ xp) {
    const int T = blockIdx.x * 256 + threadIdx.x;   // 8192 threads
    const int step = T >> 6, lane = T & 63;
    const int b = lane & 15, k = step * 32 + (lane >> 4) * 8;
    const float4_t a0 = *(const float4_t*)(x + b * IN_F + k);
    const float4_t a1 = *(const float4_t*)(x + b * IN_F + k + 4);
    half8 h;
    h2 p0 = cvt2(a0.x, a0.y), p1 = cvt2(a0.z, a0.w);
    h2 p2 = cvt2(a1.x, a1.y), p3 = cvt2(a1.z, a1.w);
    h[0]=p0[0]; h[1]=p0[1]; h[2]=p1[0]; h[3]=p1[1];
    h[4]=p2[0]; h[5]=p2[1]; h[6]=p3[0]; h[7]=p3[1];
    *(half8*)(xp + step * 512 + lane * 8) = h;
}

// ---- single-pass gemm (R10, session best 29.9us): block = otile, FULL K in
// 4 chunks of 1024 cols. LDS double-buffer 2x32KB. Wave w computes cols
// [c*1024+w*256,+256) of each chunk c, accumulating all K; 4-way cross-wave
// reduce + bias + direct store. Counted vmcnt(16) keeps the next chunk's 16
// VMEM ops in flight across every barrier (drain only before the last chunk).
// Gemm proper is pinned at ~25us (R6/R12 diagnostics) = ~3.8 TB/s pure-read
// ceiling, invariant to staging/occupancy/MLP -> structural floor.
__global__ __launch_bounds__(256) void gptq_gemm_full(
    const _Float16* __restrict__ xp, const int* __restrict__ qw,
    const float* __restrict__ scales, const float* __restrict__ zeros,
    const float* __restrict__ bias, float* __restrict__ out)
{
    __shared__ int   lq[2][16 * 512];    // 64 KB, swizzled q tiles
    __shared__ float red[4][16][17];

    const int tid  = threadIdx.x;
    const int lane = tid & 63, wave = tid >> 6;
    const int otile = blockIdx.x;
    const int ln = lane & 15, lk = lane >> 4;
    const int o  = otile * 16 + ln;
    const int x3 = ln & 7;

    // 8 (s,z) pairs for this wave: group g = c*8 + wave*2 + gi
    h2 s2g[8], c2g[8];
    #pragma unroll
    for (int c = 0; c < 4; ++c) {
        #pragma unroll
        for (int gi = 0; gi < 2; ++gi) {
            const int g = c * 8 + wave * 2 + gi;
            const float s = scales[o * GROUPS + g];
            const float z = zeros [o * GROUPS + g];
            s2g[c * 2 + gi] = cvt2(s, s);
            c2g[c * 2 + gi] = cvt2(-z * s, -z * s);   // w = q*s + (-z*s)
        }
    }
    const h2 k1024 = { (_Float16)1024.0f, (_Float16)1024.0f };

    asm volatile("s_waitcnt vmcnt(0)" ::: "memory");   // scalar loads retired
    __builtin_amdgcn_sched_barrier(0);                 // -> vmcnt counts exact

    half8 xv[2][8];
    float4_t acc = {0.f, 0.f, 0.f, 0.f};

// stage chunk C's 16 rows (this wave: 4 rows x 2 halves), src inv-swizzled
#define STAGE(C, BUF) { \
    _Pragma("unroll") \
    for (int i = 0; i < 4; ++i) { \
        const int row = wave * 4 + i; \
        const int* s0 = qw + (otile * 16 + row) * PPR + (C) * 512 \
                      + ((lane ^ (row & 7)) * 4); \
        GLOAD_LDS(s0, &lq[BUF][row * 512]); \
        GLOAD_LDS(s0 + 256, &lq[BUF][row * 512 + 256]); \
    } \
    __builtin_amdgcn_sched_barrier(0); }

// 8 x-fragment loads for chunk C (steps c*32 + wave*8 + t), contiguous 1KB each
#define XLOAD(C, BUF) { \
    const char* xc = (const char*)xp + ((C) * 32 + wave * 8) * 1024 + lane * 16; \
    asm volatile("global_load_dwordx4 %0, %1, off"             : "=v"(xv[BUF][0]) : "v"(xc)); \
    asm volatile("global_load_dwordx4 %0, %1, off offset:1024" : "=v"(xv[BUF][1]) : "v"(xc)); \
    asm volatile("global_load_dwordx4 %0, %1, off offset:2048" : "=v"(xv[BUF][2]) : "v"(xc)); \
    asm volatile("global_load_dwordx4 %0, %1, off offset:3072" : "=v"(xv[BUF][3]) : "v"(xc)); \
    const char* xd = xc + 4096; \
    asm volatile("global_load_dwordx4 %0, %1, off"             : "=v"(xv[BUF][4]) : "v"(xd)); \
    asm volatile("global_load_dwordx4 %0, %1, off offset:1024" : "=v"(xv[BUF][5]) : "v"(xd)); \
    asm volatile("global_load_dwordx4 %0, %1, off offset:2048" : "=v"(xv[BUF][6]) : "v"(xd)); \
    asm volatile("global_load_dwordx4 %0, %1, off offset:3072" : "=v"(xv[BUF][7]) : "v"(xd)); \
    __builtin_amdgcn_sched_barrier(0); }

#define WAITV16 { asm volatile("s_waitcnt vmcnt(16)" ::: "memory"); \
                  __builtin_amdgcn_sched_barrier(0); }
#define WAITV0  { asm volatile("s_waitcnt vmcnt(0)"  ::: "memory"); \
                  __builtin_amdgcn_sched_barrier(0); }
#define BARR    { __builtin_amdgcn_s_barrier(); \
                  __builtin_amdgcn_sched_barrier(0); }

// 8 steps of chunk C from buffer BUF: swizzled ds_read_b128 + dequant + MFMA
#define COMPUTE(C, BUF) { \
    _Pragma("unroll") \
    for (int t = 0; t < 8; ++t) { \
        const int4_t v = *(const int4_t*)((const char*)lq \
            + (BUF) * 32768 + ln * 2048 + (wave >> 1) * 1024 \
            + ((((wave & 1) * 32 + t * 4 + lk) ^ x3) << 4)); \
        const int sg = (C) * 2 + (t >> 2); \
        uint4_t bw; \
        _Pragma("unroll") \
        for (int i = 0; i < 4; ++i) { \
            const unsigned pv = (unsigned)v[i]; \
            const unsigned u = (pv & 0xFu) | ((pv << 12) & 0xF0000u) \
                             | 0x64006400u;            /* {1024+qlo,1024+qhi} */ \
            h2 q = __builtin_bit_cast(h2, u) - k1024;  /* exact {qlo,qhi} */ \
            h2 w = q * s2g[sg] + c2g[sg];              /* v_pk_fma_f16 */ \
            bw[i] = __builtin_bit_cast(unsigned, w); \
        } \
        acc = __builtin_amdgcn_mfma_f32_16x16x32_f16( \
            xv[BUF][t], __builtin_bit_cast(half8, bw), acc, 0, 0, 0); \
    } }

    STAGE(0, 0) XLOAD(0, 0)      // 16 in flight
    STAGE(1, 1) XLOAD(1, 1)      // 32 in flight
    WAITV16 BARR                 // chunk 0 ready (chunk 1 still in flight)
    COMPUTE(0, 0)
    BARR                         // all waves done reading buf0
    STAGE(2, 0) XLOAD(2, 0)      // 32 in flight
    WAITV16 BARR                 // chunk 1 ready (chunk 2 in flight)
    COMPUTE(1, 1)
    BARR                         // buf1 free
    STAGE(3, 1) XLOAD(3, 1)      // 32 in flight
    WAITV16 BARR                 // chunk 2 ready (chunk 3 in flight)
    COMPUTE(2, 0)
    WAITV0 BARR                  // chunk 3 ready
    COMPUTE(3, 1)

#undef STAGE
#undef XLOAD
#undef WAITV16
#undef WAITV0
#undef BARR
#undef COMPUTE

    // cross-wave k-reduce; C/D layout (m89-verified): lane holds D[(l>>4)*4+r][l&15]
    #pragma unroll
    for (int r = 0; r < 4; ++r) red[wave][lk * 4 + r][ln] = acc[r];
    __syncthreads();

    const int row = tid >> 4, col = tid & 15;
    const float sum = red[0][row][col] + red[1][row][col]
                    + red[2][row][col] + red[3][row][col];
    const int oo = otile * 16 + col;
    out[row * OUT_F + oo] = sum + bias[oo];
}

// ---- fallback (no workspace): 4-wave single-pass kernel ----
__global__ __launch_bounds__(256) void gptq_gemm_fb(
    const float* __restrict__ x, const int* __restrict__ qw,
    const float* __restrict__ scales, const float* __restrict__ zeros,
    const float* __restrict__ bias, float* __restrict__ out)
{
    const int tid  = threadIdx.x;
    const int lane = tid & 63;
    const int wave = tid >> 6;
    const int otile = blockIdx.x;
    const int ln = lane & 15, lk = lane >> 4;
    const int o = otile * 16 + ln;
    const int kc0 = wave * 1024;

    const int* qbase = qw + o * PPR + (kc0 >> 1) + lk * 4;
    const float* srow = scales + o * GROUPS;
    const float* zrow = zeros  + o * GROUPS;

    float4_t acc = {0.f, 0.f, 0.f, 0.f};
    const h2 k1024 = { (_Float16)1024.0f, (_Float16)1024.0f };

    #pragma unroll
    for (int ch = 0; ch < 4; ++ch) {
        const int cc = kc0 + ch * 256;
        h2 s2[2], c2[2];
        #pragma unroll
        for (int gi = 0; gi < 2; ++gi) {
            const float s  = srow[(cc >> 7) + gi];
            const float c0 = -zrow[(cc >> 7) + gi] * s;
            s2[gi] = cvt2(s, s); c2[gi] = cvt2(c0, c0);
        }
        #pragma unroll
        for (int t = 0; t < 8; ++t) {
            const int4_t v = *(const int4_t*)(qbase + ch * 128 + t * 16);
            const float* xq = x + ln * IN_F + cc + t * 32 + lk * 8;
            const float4_t a0 = *(const float4_t*)(xq);
            const float4_t a1 = *(const float4_t*)(xq + 4);
            half8 af;
            h2 p0 = cvt2(a0.x, a0.y), p1 = cvt2(a0.z, a0.w);
            h2 p2 = cvt2(a1.x, a1.y), p3 = cvt2(a1.z, a1.w);
            af[0]=p0[0]; af[1]=p0[1]; af[2]=p1[0]; af[3]=p1[1];
            af[4]=p2[0]; af[5]=p2[1]; af[6]=p3[0]; af[7]=p3[1];
            const int gi = t >> 2;
            uint4_t bw;
            #pragma unroll
            for (int i = 0; i < 4; ++i) {
                const unsigned pv = (unsigned)v[i];
                const unsigned u = (pv & 0xFu) | ((pv << 12) & 0xF0000u)
                                 | 0x64006400u;
                h2 q = __builtin_bit_cast(h2, u) - k1024;
                h2 w = q * s2[gi] + c2[gi];
                bw[i] = __builtin_bit_cast(unsigned, w);
            }
            acc = __builtin_amdgcn_mfma_f32_16x16x32_f16(
                af, __builtin_bit_cast(half8, bw), acc, 0, 0, 0);
        }
    }

    __shared__ float red[4][16][17];
    #pragma unroll
    for (int r = 0; r < 4; ++r) red[wave][lk * 4 + r][ln] = acc[r];
    __syncthreads();
    const int row = tid >> 4, col = tid & 15;
    const float sum = red[0][row][col] + red[1][row][col]
                    + red[2][row][col] + red[3][row][col];
    const int oo = otile * 16 + col;
    out[row * OUT_F + oo] = sum + bias[oo];
}

extern "C" void kernel_launch(void* const* d_in, const int* in_sizes, int n_in,
                              void* d_out, int out_size, void* d_ws, size_t ws_size,
                              hipStream_t stream) {
    const float* x      = (const float*)d_in[0];
    const int*   qwgt   = (const int*)d_in[1];
    const float* scales = (const float*)d_in[2];
    const float* zeros  = (const float*)d_in[3];
    const float* bias   = (const float*)d_in[4];
    float* out = (float*)d_out;

    const int nOTiles = OUT_F / 16;                    // 688

    if (d_ws && ws_size >= (size_t)(1 << 20)) {
        _Float16* xp = (_Float16*)d_ws;                // 128 KB f16 x table
        hipLaunchKernelGGL(xcvt_perm, dim3(32), dim3(256), 0, stream, x, xp);
        hipLaunchKernelGGL(gptq_gemm_full, dim3(nOTiles), dim3(256), 0, stream,
                           xp, qwgt, scales, zeros, bias, out);
    } else {
        hipLaunchKernelGGL(gptq_gemm_fb, dim3(nOTiles), dim3(256), 0, stream,
                           x, qwgt, scales, zeros, bias, out);
    }
}